// Round 5
// baseline (226.405 us; speedup 1.0000x reference)
//
#include <hip/hip_runtime.h>

#define EMBED 192
#define NPB   64          // nodes per block (== wavefront size)
#define X_HW  512
#define HW2   (X_HW*X_HW)

typedef float f32x4 __attribute__((ext_vector_type(4)));

// dinv for batch-0 grid node (ph,pw): deg = 1 + #neighbors (+1 for bug node (254,254))
__device__ __forceinline__ float dinv_b0(int ph, int pw) {
    int deg = 1 + (ph > 0) + (ph < 255) + (pw > 0) + (pw < 255)
                + ((ph == 254) & (pw == 254));
    return rsqrtf((float)deg);
}

// ---------------- Kernel A: Wf[k][co] = sum_c conv_w[c][k] * gcn_w[c][co]
__global__ __launch_bounds__(256) void wf_kernel(
    const float* __restrict__ conv_w,   // (192,12)
    const float* __restrict__ gcn_w,    // (192,192)
    float* __restrict__ wf)             // (12,192)
{
    const int idx = blockIdx.x * 256 + threadIdx.x;   // 0..2303
    const int k   = idx / EMBED;                      // 0..11
    const int co  = idx - k * EMBED;                  // 0..191
    float a0 = 0.f, a1 = 0.f, a2 = 0.f, a3 = 0.f;
#pragma unroll 4
    for (int c = 0; c < EMBED; c += 4) {
        a0 = fmaf(conv_w[(c+0)*12 + k], gcn_w[(c+0)*EMBED + co], a0);
        a1 = fmaf(conv_w[(c+1)*12 + k], gcn_w[(c+1)*EMBED + co], a1);
        a2 = fmaf(conv_w[(c+2)*12 + k], gcn_w[(c+2)*EMBED + co], a2);
        a3 = fmaf(conv_w[(c+3)*12 + k], gcn_w[(c+3)*EMBED + co], a3);
    }
    wf[idx] = (a0 + a1) + (a2 + a3);
}

// ---------------- Kernel B: wave-0 gather -> LDS cp[64][12] -> float4 matvec
__global__ __launch_bounds__(192) void fused_kernel(
    const float* __restrict__ x,     // (4,3,512,512)
    const float* __restrict__ wf,    // (12,192)
    const float* __restrict__ bias,  // (192)
    float* __restrict__ out)         // (4,65536,192)
{
    __shared__ float cp_lds[NPB][12];                // 3 KB, rows 48B (16B-aligned)
    const int tid   = threadIdx.x;                   // 0..191
    const int gbase = blockIdx.x * NPB;
    const int b     = gbase >> 16;                   // batch (blocks never straddle)

    // matvec ownership: 4 channels x 16 nodes per thread
    const int slot = tid / 48;                       // 0..3
    const int cog  = tid - slot * 48;                // 0..47
    const int co   = cog * 4;

    // prefetch weights/bias (overlaps with gather below)
    f32x4 wfr[12];
#pragma unroll
    for (int k = 0; k < 12; ++k) wfr[k] = *(const f32x4*)(wf + k * EMBED + co);
    const f32x4 bco = *(const f32x4*)(bias + co);

    // ---- gather: wave 0 only, lane ln owns node gbase+ln
    if (tid < 64) {
        const int ln = tid;
        const int n  = (gbase & 65535) + ln;
        const int ph = n >> 8, pw = n & 255;
        const float* xp0 = x + (size_t)b * 3 * HW2 + (ph * 2) * X_HW + pw * 2;
        float cp[12];
        if (b != 0) {
#pragma unroll
            for (int ic = 0; ic < 3; ++ic)
#pragma unroll
                for (int kh = 0; kh < 2; ++kh) {
                    const float2 s = *(const float2*)(xp0 + ic * HW2 + kh * X_HW);
                    cp[ic*4 + kh*2 + 0] = s.x;
                    cp[ic*4 + kh*2 + 1] = s.y;
                }
        } else {
            const float dn  = dinv_b0(ph, pw);
            const float wsf = dn * dn;
            const float wu  = (ph > 0)   ? dn * dinv_b0(ph-1, pw) : 0.f;
            const float wd  = (ph < 255) ? dn * dinv_b0(ph+1, pw) : 0.f;
            const float wl  = (pw > 0)   ? dn * dinv_b0(ph, pw-1) : 0.f;
            const float wr  = (pw < 255) ? dn * dinv_b0(ph, pw+1) : 0.f;
            // bug edge: node (254,254) receives from (255,255); dinv(255,255)=rsqrt(3)
            const float wb  = (n == 65278) ? dn * 0.5773502691896258f : 0.f;
            const int du = (ph > 0)   ? -2 * X_HW : 0;
            const int dd = (ph < 255) ?  2 * X_HW : 0;
            const int dl = (pw > 0)   ? -2 : 0;
            const int dr = (pw < 255) ?  2 : 0;
            const int db = (255 - ph) * 2 * X_HW + (255 - pw) * 2;
#pragma unroll
            for (int ic = 0; ic < 3; ++ic)
#pragma unroll
                for (int kh = 0; kh < 2; ++kh) {
                    const float* p = xp0 + ic * HW2 + kh * X_HW;
                    const float2 s  = *(const float2*)(p);
                    const float2 u  = *(const float2*)(p + du);
                    const float2 d  = *(const float2*)(p + dd);
                    const float2 l  = *(const float2*)(p + dl);
                    const float2 r  = *(const float2*)(p + dr);
                    const float2 bg = *(const float2*)(p + db);
                    cp[ic*4+kh*2+0] = wsf*s.x + wu*u.x + wd*d.x + wl*l.x + wr*r.x + wb*bg.x;
                    cp[ic*4+kh*2+1] = wsf*s.y + wu*u.y + wd*d.y + wl*l.y + wr*r.y + wb*bg.y;
                }
        }
        f32x4* row = (f32x4*)&cp_lds[ln][0];
        row[0] = (f32x4){cp[0], cp[1], cp[2],  cp[3]};
        row[1] = (f32x4){cp[4], cp[5], cp[6],  cp[7]};
        row[2] = (f32x4){cp[8], cp[9], cp[10], cp[11]};
    }
    __syncthreads();

    // ---- matvec: 16 nodes per thread, float4 channels, nontemporal stores
#pragma unroll
    for (int j = 0; j < 16; ++j) {
        const int nl = slot * 16 + j;
        const f32x4 c0 = *(const f32x4*)(&cp_lds[nl][0]);
        const f32x4 c1 = *(const f32x4*)(&cp_lds[nl][4]);
        const f32x4 c2 = *(const f32x4*)(&cp_lds[nl][8]);
        const float cps[12] = {c0.x, c0.y, c0.z, c0.w,
                               c1.x, c1.y, c1.z, c1.w,
                               c2.x, c2.y, c2.z, c2.w};
        f32x4 acc = bco;
#pragma unroll
        for (int k = 0; k < 12; ++k) {
            acc.x = fmaf(cps[k], wfr[k].x, acc.x);
            acc.y = fmaf(cps[k], wfr[k].y, acc.y);
            acc.z = fmaf(cps[k], wfr[k].z, acc.z);
            acc.w = fmaf(cps[k], wfr[k].w, acc.w);
        }
        f32x4* dst = (f32x4*)(out + (size_t)(gbase + nl) * EMBED + co);
        __builtin_nontemporal_store(acc, dst);
    }
}

extern "C" void kernel_launch(void* const* d_in, const int* in_sizes, int n_in,
                              void* d_out, int out_size, void* d_ws, size_t ws_size,
                              hipStream_t stream) {
    const float* x      = (const float*)d_in[0];
    const float* conv_w = (const float*)d_in[1];
    const float* gcn_w  = (const float*)d_in[2];
    const float* gcn_b  = (const float*)d_in[3];
    float* out = (float*)d_out;
    float* wf  = (float*)d_ws;   // 12*192 floats = 9216 B

    wf_kernel<<<9, 256, 0, stream>>>(conv_w, gcn_w, wf);

    const int n_nodes = 4 * 256 * 256;              // 262144
    fused_kernel<<<n_nodes / NPB, 192, 0, stream>>>(x, wf, gcn_b, out);
}